// Round 15
// baseline (393.923 us; speedup 1.0000x reference)
//
#include <hip/hip_runtime.h>

#define DD 48
#define TT 512
#define BB 512
#define CHK 32          // t-steps per chunk
#define RR 65           // ring rows (odd, > 2*CHK -> no producer/worker row clash)
#define RSTR 49         // ring row stride in floats (odd -> conflict-free column reads)
#define BPSTR 64        // bp row stride
#define PF 8            // producer emit ring depth

__device__ __forceinline__ float readlane_f(float v, int lane) {
  return __int_as_float(__builtin_amdgcn_readlane(__float_as_int(v), lane));
}
__device__ __forceinline__ float max3f(float a, float b, float c) {
  return fmaxf(fmaxf(a, b), c);
}
__device__ __forceinline__ unsigned min3u(unsigned a, unsigned b, unsigned c) {
  unsigned m = a < b ? a : b; return m < c ? m : c;
}

// pure value max over 48 (VCC-free, max3-fused)
__device__ __forceinline__ float vmax48(const float* s) {
  float m1[16];
#pragma unroll
  for (int k = 0; k < 16; ++k) m1[k] = max3f(s[3 * k], s[3 * k + 1], s[3 * k + 2]);
  float m2[6];
#pragma unroll
  for (int k = 0; k < 5; ++k) m2[k] = max3f(m1[3 * k], m1[3 * k + 1], m1[3 * k + 2]);
  m2[5] = m1[15];
  return fmaxf(max3f(m2[0], m2[1], m2[2]), max3f(m2[3], m2[4], m2[5]));
}

// one-time argmax with first-index ties (for btag only)
__device__ __forceinline__ int argidx48(const float* s) {
  float v1[24]; int x1[24];
#pragma unroll
  for (int k = 0; k < 24; ++k) {
    float l = s[2 * k], r = s[2 * k + 1];
    v1[k] = fmaxf(l, r); x1[k] = (r > l) ? 2 * k + 1 : 2 * k;
  }
  float v2[12]; int x2[12];
#pragma unroll
  for (int k = 0; k < 12; ++k) {
    float l = v1[2 * k], r = v1[2 * k + 1];
    v2[k] = fmaxf(l, r); x2[k] = (r > l) ? x1[2 * k + 1] : x1[2 * k];
  }
  float v3[6]; int x3[6];
#pragma unroll
  for (int k = 0; k < 6; ++k) {
    float l = v2[2 * k], r = v2[2 * k + 1];
    v3[k] = fmaxf(l, r); x3[k] = (r > l) ? x2[2 * k + 1] : x2[2 * k];
  }
  float v4[3]; int x4[3];
#pragma unroll
  for (int k = 0; k < 3; ++k) {
    float l = v3[2 * k], r = v3[2 * k + 1];
    v4[k] = fmaxf(l, r); x4[k] = (r > l) ? x3[2 * k + 1] : x3[2 * k];
  }
  float vm = fmaxf(v4[0], v4[1]);
  int xm = (v4[1] > v4[0]) ? x4[1] : x4[0];
  return (v4[2] > vm) ? x4[2] : xm;
}

__global__ __launch_bounds__(320, 1) void crf_viterbi(const float* __restrict__ logits,
                                                      const int* __restrict__ lens,
                                                      const float* __restrict__ trans,
                                                      int* __restrict__ out) {
  const int b = blockIdx.x;
  const int tid = threadIdx.x;
  const int j = tid & 63;
  const int wave = tid >> 6;            // 0 = producer, 1..4 = workers
  const int jj = j < DD ? j : DD - 1;
  const int co = j < DD ? j : DD;       // ring column (48 = dump slot)

  __shared__ float ring[2][RR][RSTR];   // [0]=alpha_t, [1]=best_t  (25.5 KB)
  __shared__ unsigned char bp[TT * BPSTR]; // 32 KB

  const float* lg = logits + (size_t)b * TT * DD;
  const int L = lens[b];
  const int steps = L - 1;                    // forward steps 1..steps
  const int nchunks = (steps + CHK - 1) / CHK;

  float tcol[DD];
#pragma unroll
  for (int i = 0; i < DD; ++i) tcol[i] = trans[i * DD + jj];

  float alpha = 0.f;
  if (wave == 0) {
    alpha = lg[jj];
    ring[0][0][co] = alpha;  // seed t=0 record
  }

  if (wave == 0) {
    __builtin_amdgcn_s_setprio(1);
    // emit ring
    float e0 = lg[1 * DD + jj], e1 = lg[2 * DD + jj],
          e2 = lg[3 * DD + jj], e3 = lg[4 * DD + jj],
          e4 = lg[5 * DD + jj], e5 = lg[6 * DD + jj],
          e6 = lg[7 * DD + jj], e7 = lg[8 * DD + jj];
    int t = 1;
    int row = 1; // t % RR, maintained incrementally

#define PSTEP(EV)                                                       \
    {                                                                   \
      float a_[DD];                                                     \
      _Pragma("unroll")                                                 \
      for (int i = 0; i < DD; ++i) a_[i] = readlane_f(alpha, i);        \
      float s_[DD];                                                     \
      _Pragma("unroll")                                                 \
      for (int i = 0; i < DD; ++i) s_[i] = a_[i] + tcol[i];             \
      float best = vmax48(s_);                                          \
      ring[1][row][co] = best;                                          \
      alpha = best + (EV);                                              \
      ring[0][row][co] = alpha;                                         \
      ++row; if (row == RR) row = 0;                                    \
    }
#define RELOAD(ES)                                  \
    {                                               \
      int r = t + PF; r = r > TT - 1 ? TT - 1 : r;  \
      ES = lg[r * DD + jj];                         \
    }

    for (int c = 0; c <= nchunks; ++c) {
      if (c < nchunks) {
        const int te = ((c + 1) * CHK < steps) ? (c + 1) * CHK : steps;
        while (t <= te) {
          PSTEP(e0); RELOAD(e0); ++t; if (t > te) break;
          PSTEP(e1); RELOAD(e1); ++t; if (t > te) break;
          PSTEP(e2); RELOAD(e2); ++t; if (t > te) break;
          PSTEP(e3); RELOAD(e3); ++t; if (t > te) break;
          PSTEP(e4); RELOAD(e4); ++t; if (t > te) break;
          PSTEP(e5); RELOAD(e5); ++t; if (t > te) break;
          PSTEP(e6); RELOAD(e6); ++t; if (t > te) break;
          PSTEP(e7); RELOAD(e7); ++t;
        }
      }
      __syncthreads();
    }
#undef PSTEP
#undef RELOAD
    __builtin_amdgcn_s_setprio(0);
  } else {
    // workers: extract bp for chunk c-1 during producer's chunk c
    for (int c = 0; c <= nchunks; ++c) {
      if (c > 0) {
        const int cc = c - 1;
        const int t0 = 1 + cc * CHK;
        const int te = ((cc + 1) * CHK < steps) ? (cc + 1) * CHK : steps;
#pragma unroll
        for (int k = 0; k < 8; ++k) {
          const int t = t0 + (wave - 1) + 4 * k;
          if (t > te) break;
          const int rp = (t - 1) % RR;
          const int rc = t % RR;
          const float4* ap = (const float4*)&ring[0][rp][0];
          float best = ring[1][rc][co];
          float a_[DD];
#pragma unroll
          for (int q = 0; q < 12; ++q) {
            float4 v = ap[q];
            a_[4 * q + 0] = v.x; a_[4 * q + 1] = v.y;
            a_[4 * q + 2] = v.z; a_[4 * q + 3] = v.w;
          }
          unsigned u[DD];
#pragma unroll
          for (int i = 0; i < DD; ++i) {
            float s = a_[i] + tcol[i];          // bit-identical to producer's s_i
            u[i] = (s == best) ? (unsigned)i : 64u; // value-eq == argmax tie semantics
          }
          unsigned n1[16];
#pragma unroll
          for (int kk = 0; kk < 16; ++kk)
            n1[kk] = min3u(u[3 * kk], u[3 * kk + 1], u[3 * kk + 2]);
          unsigned n2[6];
#pragma unroll
          for (int kk = 0; kk < 5; ++kk)
            n2[kk] = min3u(n1[3 * kk], n1[3 * kk + 1], n1[3 * kk + 2]);
          n2[5] = n1[15];
          unsigned idx = min3u(min3u(n2[0], n2[1], n2[2]),
                               min3u(n2[3], n2[4], n2[5]), 63u);
          bp[t * BPSTR + j] = (unsigned char)idx;
        }
      }
      __syncthreads();
    }
  }

  // ---- epilogue ----
  int* ob = out + (size_t)b * TT;

  if (wave == 0) {
    // last_tag from final alpha (held in producer registers)
    float af[DD];
#pragma unroll
    for (int i = 0; i < DD; ++i) af[i] = readlane_f(alpha, i);
    int btag = argidx48(af);
    if (j == 0) ob[L - 1] = btag;

    // backtrack: H' = bp_t[H] via shfl composition
    int H = j;
    for (int tt = L - 1; tt >= 1; --tt) {
      int v = bp[tt * BPSTR + jj];
      H = __shfl(v, H, 64);
      if (j == btag) ob[tt - 1] = H;
    }
  }

  // zero the padded tail t >= L (all 320 threads)
  for (int tt = L + tid; tt < TT; tt += 320) ob[tt] = 0;
}

extern "C" void kernel_launch(void* const* d_in, const int* in_sizes, int n_in,
                              void* d_out, int out_size, void* d_ws, size_t ws_size,
                              hipStream_t stream) {
  const float* logits = (const float*)d_in[0];
  const int* lens     = (const int*)d_in[1];
  const float* trans  = (const float*)d_in[2];
  int* out            = (int*)d_out;
  (void)in_sizes; (void)n_in; (void)out_size; (void)d_ws; (void)ws_size;
  crf_viterbi<<<BB, 320, 0, stream>>>(logits, lens, trans, out);
}

// Round 16
// 251.651 us; speedup vs baseline: 1.5654x; 1.5654x over previous
//
#include <hip/hip_runtime.h>

#define DD 48
#define TT 512
#define BB 512
#define PF 8
#define AWS_STRIDE 64
#define AWS_BYTES ((size_t)BB * TT * AWS_STRIDE * 4)   // 67,108,864
#define BPWS_BYTES ((size_t)BB * TT * DD)              // 12,582,912
#define WS_NEED (AWS_BYTES + BPWS_BYTES)

__device__ __forceinline__ float readlane_f(float v, int lane) {
  return __int_as_float(__builtin_amdgcn_readlane(__float_as_int(v), lane));
}
__device__ __forceinline__ float max3f(float a, float b, float c) {
  return fmaxf(fmaxf(a, b), c);
}

// pure value max over 48 (VCC-free, ~24 ops)
__device__ __forceinline__ float vmax48(const float* s) {
  float m1[16];
#pragma unroll
  for (int k = 0; k < 16; ++k) m1[k] = max3f(s[3 * k], s[3 * k + 1], s[3 * k + 2]);
  float m2[6];
#pragma unroll
  for (int k = 0; k < 5; ++k) m2[k] = max3f(m1[3 * k], m1[3 * k + 1], m1[3 * k + 2]);
  m2[5] = m1[15];
  return fmaxf(max3f(m2[0], m2[1], m2[2]), max3f(m2[3], m2[4], m2[5]));
}

// argmax with first-index ties (strict > moves right)
__device__ __forceinline__ int argidx48(const float* s) {
  float v1[24]; int x1[24];
#pragma unroll
  for (int k = 0; k < 24; ++k) {
    float l = s[2 * k], r = s[2 * k + 1];
    v1[k] = fmaxf(l, r); x1[k] = (r > l) ? 2 * k + 1 : 2 * k;
  }
  float v2[12]; int x2[12];
#pragma unroll
  for (int k = 0; k < 12; ++k) {
    float l = v1[2 * k], r = v1[2 * k + 1];
    v2[k] = fmaxf(l, r); x2[k] = (r > l) ? x1[2 * k + 1] : x1[2 * k];
  }
  float v3[6]; int x3[6];
#pragma unroll
  for (int k = 0; k < 6; ++k) {
    float l = v2[2 * k], r = v2[2 * k + 1];
    v3[k] = fmaxf(l, r); x3[k] = (r > l) ? x2[2 * k + 1] : x2[2 * k];
  }
  float v4[3]; int x4[3];
#pragma unroll
  for (int k = 0; k < 3; ++k) {
    float l = v3[2 * k], r = v3[2 * k + 1];
    v4[k] = fmaxf(l, r); x4[k] = (r > l) ? x3[2 * k + 1] : x3[2 * k];
  }
  float vm = fmaxf(v4[0], v4[1]);
  int xm = (v4[1] > v4[0]) ? x4[1] : x4[0];
  return (v4[2] > vm) ? x4[2] : xm;
}

// ---------------- kernel 1: serial forward, value chain only ----------------
__global__ __launch_bounds__(64, 1) void crf_fwd(const float* __restrict__ logits,
                                                 const int* __restrict__ lens,
                                                 const float* __restrict__ trans,
                                                 float* __restrict__ aws) {
  const int b = blockIdx.x;
  const int j = threadIdx.x;
  const int jj = j < DD ? j : DD - 1;

  float tcol[DD];
#pragma unroll
  for (int i = 0; i < DD; ++i) tcol[i] = trans[i * DD + jj];

  const float* lg = logits + (size_t)b * TT * DD;
  const int L = lens[b];

  float alpha = lg[jj];
  float* ar = aws + (size_t)b * TT * AWS_STRIDE; // row t pointer
  ar[j] = alpha;                                 // seed row 0 (cols 48..63 pad)
  ar += AWS_STRIDE;

  float e0 = lg[1 * DD + jj], e1 = lg[2 * DD + jj],
        e2 = lg[3 * DD + jj], e3 = lg[4 * DD + jj],
        e4 = lg[5 * DD + jj], e5 = lg[6 * DD + jj],
        e6 = lg[7 * DD + jj], e7 = lg[8 * DD + jj];

#define STEP(EV)                                                    \
  {                                                                 \
    float a_[DD];                                                   \
    _Pragma("unroll")                                               \
    for (int i = 0; i < DD; ++i) a_[i] = readlane_f(alpha, i);      \
    float s_[DD];                                                   \
    _Pragma("unroll")                                               \
    for (int i = 0; i < DD; ++i) s_[i] = a_[i] + tcol[i];           \
    float best = vmax48(s_);                                        \
    alpha = best + (EV);                                            \
    ar[j] = alpha;                                                  \
    ar += AWS_STRIDE;                                               \
  }
#define RELOAD(ES)                                 \
  {                                                \
    int r = t + PF; r = r > TT - 1 ? TT - 1 : r;   \
    ES = lg[r * DD + jj];                          \
  }

  int t = 1;
  while (t < L) {
    STEP(e0); RELOAD(e0); ++t; if (t >= L) break;
    STEP(e1); RELOAD(e1); ++t; if (t >= L) break;
    STEP(e2); RELOAD(e2); ++t; if (t >= L) break;
    STEP(e3); RELOAD(e3); ++t; if (t >= L) break;
    STEP(e4); RELOAD(e4); ++t; if (t >= L) break;
    STEP(e5); RELOAD(e5); ++t; if (t >= L) break;
    STEP(e6); RELOAD(e6); ++t; if (t >= L) break;
    STEP(e7); RELOAD(e7); ++t;
  }
#undef STEP
#undef RELOAD
}

// ---------------- kernel 2: parallel bp extraction from stored alphas ------
__global__ __launch_bounds__(64) void crf_bpx(const float* __restrict__ aws,
                                              const int* __restrict__ lens,
                                              const float* __restrict__ trans,
                                              unsigned char* __restrict__ bpws) {
  const int gb = blockIdx.x;        // BB * 128 blocks
  const int b = gb >> 7;
  const int t0 = ((gb & 127) << 2) + 1; // 1,5,...,509
  const int j = threadIdx.x;
  const int jj = j < DD ? j : DD - 1;
  const int L = lens[b];
  if (t0 >= L) return;              // wave-uniform

  float tcol[DD];
#pragma unroll
  for (int i = 0; i < DD; ++i) tcol[i] = trans[i * DD + jj];

#pragma unroll
  for (int k = 0; k < 4; ++k) {
    const int t = t0 + k;
    if (t >= L) break;              // wave-uniform
    float aval = aws[((size_t)b * TT + (t - 1)) * AWS_STRIDE + jj];
    float s_[DD];
#pragma unroll
    for (int i = 0; i < DD; ++i) s_[i] = readlane_f(aval, i) + tcol[i];
    int idx = argidx48(s_);
    if (j < DD) bpws[((size_t)b * TT + t) * DD + j] = (unsigned char)idx;
  }
}

// ---------------- kernel 3: backtrack (compose) + tail zero -----------------
__global__ __launch_bounds__(64, 1) void crf_btr(const float* __restrict__ aws,
                                                 const int* __restrict__ lens,
                                                 const unsigned char* __restrict__ bpws,
                                                 int* __restrict__ out) {
  const int b = blockIdx.x;
  const int j = threadIdx.x;
  const int jj = j < DD ? j : DD - 1;
  const int L = lens[b];

  // last tag from final alpha row
  float av = aws[((size_t)b * TT + (L - 1)) * AWS_STRIDE + jj];
  float af[DD];
#pragma unroll
  for (int i = 0; i < DD; ++i) af[i] = readlane_f(av, i);
  const int btag = argidx48(af);

  int* ob = out + (size_t)b * TT;
  if (j == 0) ob[L - 1] = btag;

  // compose H' = bp_t[H] with an 8-deep static prefetch ring on bp rows
  const unsigned char* bpb = bpws + (size_t)b * TT * DD;
#define BPROW(T) (int)bpb[((T) > 0 ? (T) : 0) * DD + jj]
  int v0 = BPROW(L - 1), v1 = BPROW(L - 2), v2 = BPROW(L - 3), v3 = BPROW(L - 4),
      v4 = BPROW(L - 5), v5 = BPROW(L - 6), v6 = BPROW(L - 7), v7 = BPROW(L - 8);

  int H = j;
  int t = L - 1;
#define CSTEP(VS)                                  \
  {                                                \
    H = __shfl((VS), H, 64);                       \
    if (j == btag) ob[t - 1] = H;                  \
    VS = BPROW(t - 8);                             \
    --t;                                           \
  }
  while (t >= 1) {
    CSTEP(v0); if (t < 1) break;
    CSTEP(v1); if (t < 1) break;
    CSTEP(v2); if (t < 1) break;
    CSTEP(v3); if (t < 1) break;
    CSTEP(v4); if (t < 1) break;
    CSTEP(v5); if (t < 1) break;
    CSTEP(v6); if (t < 1) break;
    CSTEP(v7);
  }
#undef CSTEP
#undef BPROW

  // zero the padded tail t >= L
  for (int tt = L + j; tt < TT; tt += 64) ob[tt] = 0;
}

// ---------------- fallback (ws too small): R10 single-kernel ----------------
__global__ __launch_bounds__(64, 1) void crf_fallback(const float* __restrict__ logits,
                                                      const int* __restrict__ lens,
                                                      const float* __restrict__ trans,
                                                      int* __restrict__ out) {
  const int b = blockIdx.x;
  const int j = threadIdx.x;
  const int jj = j < DD ? j : DD - 1;
  __shared__ unsigned char bp[TT * 64];

  float tcol[DD];
#pragma unroll
  for (int i = 0; i < DD; ++i) tcol[i] = trans[i * DD + jj];
  const float* lg = logits + (size_t)b * TT * DD;
  const int L = lens[b];
  float alpha = lg[jj];

  float e0 = lg[1 * DD + jj], e1 = lg[2 * DD + jj],
        e2 = lg[3 * DD + jj], e3 = lg[4 * DD + jj],
        e4 = lg[5 * DD + jj], e5 = lg[6 * DD + jj],
        e6 = lg[7 * DD + jj], e7 = lg[8 * DD + jj];

#define STEP(EV)                                                    \
  {                                                                 \
    float s_[DD];                                                   \
    _Pragma("unroll")                                               \
    for (int i = 0; i < DD; ++i) s_[i] = readlane_f(alpha, i) + tcol[i]; \
    float best = vmax48(s_);                                        \
    int idx = argidx48(s_);                                         \
    alpha = best + (EV);                                            \
    bp[t * 64 + j] = (unsigned char)idx;                            \
  }
#define RELOAD(ES)                                 \
  {                                                \
    int r = t + PF; r = r > TT - 1 ? TT - 1 : r;   \
    ES = lg[r * DD + jj];                          \
  }
  int t = 1;
  while (t < L) {
    STEP(e0); RELOAD(e0); ++t; if (t >= L) break;
    STEP(e1); RELOAD(e1); ++t; if (t >= L) break;
    STEP(e2); RELOAD(e2); ++t; if (t >= L) break;
    STEP(e3); RELOAD(e3); ++t; if (t >= L) break;
    STEP(e4); RELOAD(e4); ++t; if (t >= L) break;
    STEP(e5); RELOAD(e5); ++t; if (t >= L) break;
    STEP(e6); RELOAD(e6); ++t; if (t >= L) break;
    STEP(e7); RELOAD(e7); ++t;
  }
#undef STEP
#undef RELOAD
  __syncthreads();

  float af[DD];
#pragma unroll
  for (int i = 0; i < DD; ++i) af[i] = readlane_f(alpha, i);
  int btag = argidx48(af);
  int* ob = out + (size_t)b * TT;
  if (j == 0) ob[L - 1] = btag;
  int H = j;
  for (int tt = L - 1; tt >= 1; --tt) {
    int v = bp[tt * 64 + jj];
    H = __shfl(v, H, 64);
    if (j == btag) ob[tt - 1] = H;
  }
  for (int tt = L + j; tt < TT; tt += 64) ob[tt] = 0;
}

extern "C" void kernel_launch(void* const* d_in, const int* in_sizes, int n_in,
                              void* d_out, int out_size, void* d_ws, size_t ws_size,
                              hipStream_t stream) {
  const float* logits = (const float*)d_in[0];
  const int* lens     = (const int*)d_in[1];
  const float* trans  = (const float*)d_in[2];
  int* out            = (int*)d_out;
  (void)in_sizes; (void)n_in; (void)out_size;

  if (ws_size >= WS_NEED) {
    float* aws = (float*)d_ws;
    unsigned char* bpws = (unsigned char*)d_ws + AWS_BYTES;
    crf_fwd<<<BB, 64, 0, stream>>>(logits, lens, trans, aws);
    crf_bpx<<<BB * 128, 64, 0, stream>>>(aws, lens, trans, bpws);
    crf_btr<<<BB, 64, 0, stream>>>(aws, lens, bpws, out);
  } else {
    crf_fallback<<<BB, 64, 0, stream>>>(logits, lens, trans, out);
  }
}